// Round 5
// baseline (210.854 us; speedup 1.0000x reference)
//
#include <hip/hip_runtime.h>

// SimVQuantizer: B=8, D=128 (N_CB=8 x CDIM=16), H=W=32 -> 8192 pixels.
// Outputs (FLOAT32, concatenated flat):
//   quantized  [8,128,32,32]  = 1048576   @ 0
//   indices    [8,8,32,32]    =   65536   @ 1048576
//   commitment scalar         =       1   @ 1114112
//   new_codebooks [8,1024,16] =  131072   @ 1114113
//   new_count  [8,1024]       =    8192   @ 1245185
//   new_weight [8,1024,16]    =  131072   @ 1253377

#define NCB   8
#define VOCAB 1024
#define CDIM  16
#define NPIX  8192   // B*H*W
#define HW    1024   // H*W

#define OFF_QUANT  0
#define OFF_IDX    1048576
#define OFF_COMMIT 1114112
#define OFF_NCB    1114113
#define OFF_NCNT   1245185
#define OFF_NWT    1253377

// workspace layout (floats): counts[8*1024], sums[8*1024*16], then a double
#define WS_COUNTS_OFF 0
#define WS_SUMS_OFF   (NCB * VOCAB)
#define WS_COMMIT_BYTE_OFF (size_t)((NCB * VOCAB) * 4 + (NCB * VOCAB * CDIM) * 4) // 557056
#define WS_ZERO_BYTES (WS_COMMIT_BYTE_OFF + 8)

typedef float v2f __attribute__((ext_vector_type(2)));

// numpy pairwise_sum (order-preserving 8-accumulator) for n=16:
// r[j] = a[j] + a[j+8];  res = ((r0+r1)+(r2+r3)) + ((r4+r5)+(r6+r7))
__device__ __forceinline__ float npsum16(const float m[16]) {
#pragma clang fp contract(off)
  float r0 = m[0] + m[8];
  float r1 = m[1] + m[9];
  float r2 = m[2] + m[10];
  float r3 = m[3] + m[11];
  float r4 = m[4] + m[12];
  float r5 = m[5] + m[13];
  float r6 = m[6] + m[14];
  float r7 = m[7] + m[15];
  return ((r0 + r1) + (r2 + r3)) + ((r4 + r5) + (r6 + r7));
}

__device__ __forceinline__ float npsum16sq(const float a[16]) {
#pragma clang fp contract(off)
  float m[16];
#pragma unroll
  for (int d = 0; d < 16; ++d) m[d] = a[d] * a[d];
  return npsum16(m);
}

// 1024 blocks x 512 threads. Block: c = bx>>7, pchunk = bx&127 (64 pixels).
// Lane = pixel. Wave w scans the CONTIGUOUS vocab slice [w*128, w*128+128);
// the slice base is readfirstlane-forced wave-uniform so codebook fetches
// become s_load (SGPR broadcast) -> no VALU/LDS cost for operand fetch.
__global__ __launch_bounds__(512, 8) void k_assign(
    const float* __restrict__ z, const float* __restrict__ cb,
    float* __restrict__ out, float* __restrict__ ws_counts,
    float* __restrict__ ws_sums, double* __restrict__ ws_commit) {
  __shared__ float s_c2[VOCAB];   // 4KB
  __shared__ float s_best[512];   // 2KB
  __shared__ int s_bi[512];       // 2KB

  const int c = blockIdx.x >> 7;
  const int pchunk = blockIdx.x & 127;
  const int t = threadIdx.x;
  const int pix = t & 63;
  const int w = __builtin_amdgcn_readfirstlane(t >> 6);  // wave-uniform

  const float* cbc = cb + (size_t)c * VOCAB * CDIM;

  // ||cb||^2 for all 1024 entries (np.sum(cb*cb,-1), pairwise 8-acc order)
  for (int v = t; v < VOCAB; v += 512) {
    float e[16];
#pragma unroll
    for (int d = 0; d < 16; ++d) e[d] = cbc[(size_t)v * CDIM + d];
    s_c2[v] = npsum16sq(e);
  }
  __syncthreads();

  const int n = pchunk * 64 + pix;  // pixel id in [0, 8192)
  const int b = n >> 10;            // batch
  const int hw = n & 1023;          // h*W + w

  // zp[n,c,d] = z[b, c*16+d, h, w]; 64-lane coalesced per d
  const float* zbase = z + ((size_t)(b * 128 + c * 16)) * HW + hw;
  float zv[16];
#pragma unroll
  for (int d = 0; d < 16; ++d) zv[d] = zbase[(size_t)d * HW];

  const float z2 = npsum16sq(zv);

  // pack z into float2 pairs once (for v_pk_* packed fp32 ops)
  v2f Z[8];
#pragma unroll
  for (int j = 0; j < 8; ++j) Z[j] = (v2f){zv[2 * j], zv[2 * j + 1]};

  float best = INFINITY;
  int bi = 0;
  const int vbase = w * 128;
  const float4* e4 =
      reinterpret_cast<const float4*>(cbc + (size_t)vbase * CDIM);

#pragma unroll 2
  for (int vo = 0; vo < 128; ++vo) {
    // wave-uniform address -> s_load_dwordx4 x4 (SMEM pipe, SGPR broadcast)
    const float4 q0 = e4[vo * 4 + 0];
    const float4 q1 = e4[vo * 4 + 1];
    const float4 q2 = e4[vo * 4 + 2];
    const float4 q3 = e4[vo * 4 + 3];
    float d2;
    {
#pragma clang fp contract(off)
      // exact numpy-einsum order via packed fp32 (bit-identical per element):
      // l_j = (m_j + m_{j+4}) + (m_{j+8} + m_{j+12}); res = (l0+l1)+(l2+l3)
      const v2f M0 = Z[0] * (v2f){q0.x, q0.y};  // (m0,m1)
      const v2f M1 = Z[1] * (v2f){q0.z, q0.w};  // (m2,m3)
      const v2f M2 = Z[2] * (v2f){q1.x, q1.y};  // (m4,m5)
      const v2f M3 = Z[3] * (v2f){q1.z, q1.w};  // (m6,m7)
      const v2f M4 = Z[4] * (v2f){q2.x, q2.y};  // (m8,m9)
      const v2f M5 = Z[5] * (v2f){q2.z, q2.w};  // (m10,m11)
      const v2f M6 = Z[6] * (v2f){q3.x, q3.y};  // (m12,m13)
      const v2f M7 = Z[7] * (v2f){q3.z, q3.w};  // (m14,m15)
      const v2f A = M0 + M2;   // (m0+m4,  m1+m5)
      const v2f Bp = M1 + M3;  // (m2+m6,  m3+m7)
      const v2f C = M4 + M6;   // (m8+m12, m9+m13)
      const v2f D = M5 + M7;   // (m10+m14,m11+m15)
      const v2f E = A + C;     // (l0, l1)
      const v2f F = Bp + D;    // (l2, l3)
      const float dot = (E.x + E.y) + (F.x + F.y);
      d2 = (z2 - 2.0f * dot) + s_c2[vbase + vo];  // np: (z2-2*einsum)+c2
    }
    const bool lt = d2 < best;  // strict <, ascending v -> first-wins
    best = lt ? d2 : best;
    bi = lt ? (vbase + vo) : bi;
  }
  s_best[w * 64 + pix] = best;
  s_bi[w * 64 + pix] = bi;
  __syncthreads();

  // wave 0: combine the 8 contiguous slice minima in ascending slice order
  // (strict < keeps lowest index among equal minima = np.argmin first-wins;
  // tie-break kept for safety).
  if (t < 64) {
    best = s_best[t];
    bi = s_bi[t];
#pragma unroll
    for (int s = 1; s < 8; ++s) {
      const float ob = s_best[s * 64 + t];
      const int oi = s_bi[s * 64 + t];
      const bool take = (ob < best) || (ob == best && oi < bi);
      best = take ? ob : best;
      bi = take ? oi : bi;
    }

    // gather winning entry (L2-hot), write outputs
    const float* qe = cbc + (size_t)bi * CDIM;
    float comm = 0.f;
#pragma unroll
    for (int d = 0; d < 16; ++d) {
      float zq = qe[d];
      float diff, qst;
      {
#pragma clang fp contract(off)
        diff = zv[d] - zq;
        qst = zv[d] + (zq - zv[d]);  // zq_st = zp + (zq - zp), as np computes
      }
      comm += diff * diff;
      out[OFF_QUANT + ((size_t)(b * 128 + c * 16 + d)) * HW + hw] = qst;
    }
    out[OFF_IDX + ((size_t)(b * NCB + c)) * HW + hw] = (float)bi;

    atomicAdd(&ws_counts[c * VOCAB + bi], 1.0f);
#pragma unroll
    for (int d = 0; d < 16; ++d)
      atomicAdd(&ws_sums[((size_t)(c * VOCAB + bi)) * CDIM + d], zv[d]);

    // commitment: reduce across wave 0's 64 lanes, one f64 atomic per block
#pragma unroll
    for (int off = 32; off; off >>= 1) comm += __shfl_down(comm, off);
    if (t == 0) atomicAdd(ws_commit, (double)comm);
  }
}

// EMA update + Laplace-smoothed normalization. 128 blocks x 256 threads:
// block = (c, part of 16); each block recomputes its c's nsum (L2-cached),
// then writes a coalesced 1/16 slice of the outputs.
__global__ __launch_bounds__(256) void k_update(
    const float* __restrict__ ema_count, const float* __restrict__ ema_weight,
    const float* __restrict__ ws_counts, const float* __restrict__ ws_sums,
    const double* __restrict__ ws_commit, float* __restrict__ out) {
  const int c = blockIdx.x >> 4;
  const int part = blockIdx.x & 15;
  const int t = threadIdx.x;
  __shared__ float s_red[4];
  __shared__ float s_n;

  float psum = 0.f;
#pragma unroll
  for (int k = 0; k < 4; ++k) {
    const int v = k * 256 + t;
    psum += 0.99f * ema_count[c * VOCAB + v] + 0.01f * ws_counts[c * VOCAB + v];
  }
#pragma unroll
  for (int off = 32; off; off >>= 1) psum += __shfl_down(psum, off);
  if ((t & 63) == 0) s_red[t >> 6] = psum;
  __syncthreads();
  if (t == 0) s_n = (s_red[0] + s_red[1]) + (s_red[2] + s_red[3]);
  __syncthreads();
  const float nsum = s_n;
  const float veps = 0.01024f;  // VOCAB * 1e-5

  // new_count: 64 entries per block
  if (t < 64) {
    const int v = part * 64 + t;
    out[OFF_NCNT + c * VOCAB + v] =
        0.99f * ema_count[c * VOCAB + v] + 0.01f * ws_counts[c * VOCAB + v];
  }

  // new_weight / new_codebooks: 1024 elements per block, coalesced
#pragma unroll
  for (int k = 0; k < 4; ++k) {
    const int i = part * 1024 + k * 256 + t;  // element within codebook c
    const int v = i >> 4;
    const float nc =
        0.99f * ema_count[c * VOCAB + v] + 0.01f * ws_counts[c * VOCAB + v];
    const float cnt = (nc + 1e-5f) / (nsum + veps) * nsum;
    const size_t gi = (size_t)c * VOCAB * CDIM + i;
    const float nw = 0.99f * ema_weight[gi] + 0.01f * ws_sums[gi];
    out[OFF_NWT + gi] = nw;
    out[OFF_NCB + gi] = nw / cnt;
  }
  if (blockIdx.x == 0 && t == 0)
    out[OFF_COMMIT] = (float)(*ws_commit / 1048576.0);
}

extern "C" void kernel_launch(void* const* d_in, const int* in_sizes, int n_in,
                              void* d_out, int out_size, void* d_ws,
                              size_t ws_size, hipStream_t stream) {
  const float* z = (const float*)d_in[0];
  const float* codebooks = (const float*)d_in[1];
  const float* ema_count = (const float*)d_in[2];
  const float* ema_weight = (const float*)d_in[3];
  float* out = (float*)d_out;

  float* wsf = (float*)d_ws;
  float* ws_counts = wsf + WS_COUNTS_OFF;
  float* ws_sums = wsf + WS_SUMS_OFF;
  double* ws_commit = (double*)((char*)d_ws + WS_COMMIT_BYTE_OFF);

  hipMemsetAsync(d_ws, 0, WS_ZERO_BYTES, stream);

  k_assign<<<dim3(1024), dim3(512), 0, stream>>>(z, codebooks, out, ws_counts,
                                                 ws_sums, ws_commit);
  k_update<<<dim3(128), dim3(256), 0, stream>>>(ema_count, ema_weight,
                                                ws_counts, ws_sums, ws_commit,
                                                out);
}